// Round 9
// baseline (209.441 us; speedup 1.0000x reference)
//
#include <hip/hip_runtime.h>
#include <hip/hip_bf16.h>
#include <math.h>

#define SS 2048
#define HH 1024
#define NHH 16
#define HDD 64
#define BH 32
#define MM 4096

typedef unsigned short u16;
using bf16x8 = __attribute__((ext_vector_type(8))) short;
using floatx4 = __attribute__((ext_vector_type(4))) float;

__device__ __forceinline__ u16 f2bf(float f) {
  unsigned u = __float_as_uint(f);
  u += 0x7fffu + ((u >> 16) & 1u);
  return (u16)(u >> 16);
}
__device__ __forceinline__ unsigned pk_bf16(float a, float b) {
  union { __hip_bfloat162 h2; unsigned u; } c;
  c.h2 = __float22bfloat162_rn(float2{a, b});
  return c.u;
}
// single-instruction packed f32->bf16 (RNE). No builtin on gfx950 (m240).
__device__ __forceinline__ unsigned pk_asm(float a, float b) {
  unsigned r;
  asm("v_cvt_pk_bf16_f32 %0, %1, %2" : "=v"(r) : "v"(a), "v"(b));
  return r;
}
__device__ __forceinline__ void gload_lds16(const u16* g, u16* l) {
  __builtin_amdgcn_global_load_lds(
      (const __attribute__((address_space(1))) void*)g,
      (__attribute__((address_space(3))) void*)l, 16, 0, 0);
}

// ---------------------------------------------------------------------------
// fp32 -> bf16 conversion (hs + 4 weights) + RoPE cos/sin table.
// ---------------------------------------------------------------------------
__global__ __launch_bounds__(256) void convert_bf(
    const float* __restrict__ hs, const float* __restrict__ wq,
    const float* __restrict__ wk, const float* __restrict__ wv,
    const float* __restrict__ wo, const int* __restrict__ pos,
    u16* __restrict__ hs_b, u16* __restrict__ wq_b, u16* __restrict__ wk_b,
    u16* __restrict__ wv_b, u16* __restrict__ wo_b,
    float2* __restrict__ tab) {
  int g = blockIdx.x * 256 + threadIdx.x;
  if (g < 2097152) {
    const float* src;
    u16* dst;
    int off;
    if (g < 1048576) {
      src = hs; dst = hs_b; off = g;
    } else {
      int t = g - 1048576;
      int w = t >> 18;
      off = t & 262143;
      src = (w == 0) ? wq : (w == 1) ? wk : (w == 2) ? wv : wo;
      dst = (w == 0) ? wq_b : (w == 1) ? wk_b : (w == 2) ? wv_b : wo_b;
    }
    float4 v = ((const float4*)src)[off];
    ushort4 o = make_ushort4(f2bf(v.x), f2bf(v.y), f2bf(v.z), f2bf(v.w));
    ((ushort4*)dst)[off] = o;
  } else {
    int idx = g - 2097152;  // 0..65535
    int s = idx >> 5, j = idx & 31;
    float p = (float)pos[s];
    const float c0 = 13.287712379549449f / 32.0f;  // log2(10000)/32
    float f = p * exp2f(-(float)j * c0);
    float sn, cs;
    sincosf(f, &sn, &cs);
    tab[idx] = float2{cs, sn};
  }
}

// ---------------------------------------------------------------------------
// QKV GEMM, 8-phase 256x256 schedule (T2+T3+T4+T5), BK=64, 8 waves (2Mx4N),
// 128 KB STATIC LDS double-buffer, counted vmcnt(6) once per K-tile.
// (unchanged from R3 — verified correct; ~44 us, limited by 192/256 CU fill)
// ---------------------------------------------------------------------------
__global__ __launch_bounds__(512, 2) void mfma_gemm_qkv(
    const u16* __restrict__ X, const u16* __restrict__ W0,
    const u16* __restrict__ W1, const u16* __restrict__ W2,
    const float* __restrict__ b0, const float* __restrict__ b1,
    const float* __restrict__ b2, const float2* __restrict__ tab,
    u16* __restrict__ O0, u16* __restrict__ O1, u16* __restrict__ O2) {
  __shared__ __align__(16) u16 lds[65536];  // 128 KB static
  const int tid = threadIdx.x;
  const int lane = tid & 63;
  const int wv = __builtin_amdgcn_readfirstlane(tid >> 6);
  const int l15 = lane & 15, quad = lane >> 4;
  const int sw7 = l15 & 7;
  const int wm = wv >> 2, wn = wv & 3;
  const int r8 = lane >> 3, c7 = lane & 7;

  // XCD-aware bijective swizzle: XCD x gets 24 contiguous (by,bx) tiles.
  int wg = blockIdx.x;
  int swz = (wg & 7) * 24 + (wg >> 3);
  int bx = swz % 12, by = swz / 12;
  const int m0 = by * 256;
  const int n0g = bx * 256;
  const int wsel = n0g >> 10;
  const int n0 = n0g & 1023;
  const u16* Wsel = (wsel == 1) ? W1 : (wsel == 2) ? W2 : W0;
  const float* bsel = (wsel == 1) ? b1 : (wsel == 2) ? b2 : b0;
  u16* Osel = (wsel == 1) ? O1 : (wsel == 2) ? O2 : O0;

  u16* const ldsA = lds;            // [buf][256][64] u16
  u16* const ldsB = lds + 32768;

  // per-unit global sources (2 gloads each), pre-swizzled chunk c7^r8
  const int csw = (c7 ^ r8) * 8;
  const int rA0 = (wv >> 2) * 128 + (wv & 3) * 16;  // UA_p0 per-wave base row
  const int rB0 = (wv >> 1) * 64 + (wv & 1) * 16;   // UB_p0 per-wave base row
  const u16* gA0a = X + (size_t)(m0 + rA0 + r8) * HH + csw;
  const u16* gA0b = gA0a + 8 * HH;
  const u16* gA2a = gA0a + 64 * HH;
  const u16* gA2b = gA0a + 72 * HH;
  const u16* gB0a = Wsel + (size_t)(n0 + rB0 + r8) * HH + csw;
  const u16* gB0b = gB0a + 8 * HH;
  const u16* gB1a = gB0a + 32 * HH;
  const u16* gB1b = gB0a + 40 * HH;
  // LDS dst offsets (u16), within buf (buf stride 16384)
  const int dA0 = rA0 * 64;
  const int dA2 = dA0 + 4096;   // +64 rows
  const int dB0 = rB0 * 64;
  const int dB1 = dB0 + 2048;   // +32 rows

#define STAGEU(pa, pb, base, doff, buf)                  \
  do {                                                   \
    u16* d_ = (base) + (buf) * 16384 + (doff);           \
    gload_lds16((pa), d_);                               \
    gload_lds16((pb), d_ + 512);                         \
  } while (0)

  floatx4 acc[8][4];
#pragma unroll
  for (int i = 0; i < 8; ++i)
#pragma unroll
    for (int j = 0; j < 4; ++j) acc[i][j] = (floatx4){0.f, 0.f, 0.f, 0.f};

  // prologue: tile0 all 4 units, tile1 {UA_p0, UB_p0, UA_p2} (7 units);
  // UB_p1(1) arrives at t0/p0. vmcnt(6) -> tile0 landed, tile1's 3 in flight.
  STAGEU(gA0a, gA0b, ldsA, dA0, 0);
  STAGEU(gA2a, gA2b, ldsA, dA2, 0);
  STAGEU(gB0a, gB0b, ldsB, dB0, 0);
  STAGEU(gB1a, gB1b, ldsB, dB1, 0);
  STAGEU(gA0a + 64, gA0b + 64, ldsA, dA0, 1);
  STAGEU(gB0a + 64, gB0b + 64, ldsB, dB0, 1);
  STAGEU(gA2a + 64, gA2b + 64, ldsA, dA2, 1);
  asm volatile("s_waitcnt vmcnt(6)" ::: "memory");
  __builtin_amdgcn_s_barrier();

  // running prefetch pointers (u16 offsets advance 64 per tile)
  const u16 *pUB1a = gB1a + 64, *pUB1b = gB1b + 64;      // next target: tile 1
  const u16 *pUA0a = gA0a + 128, *pUA0b = gA0b + 128;    // next target: tile 2
  const u16 *pUB0a = gB0a + 128, *pUB0b = gB0b + 128;
  const u16 *pUA2a = gA2a + 128, *pUA2b = gA2b + 128;

  bf16x8 af[4][2], bf0[2][2], bf1[2][2];

#define LOADA(Ab, hm)                                                     \
  _Pragma("unroll") for (int mb = 0; mb < 4; ++mb) {                      \
    const u16* rp_ = (Ab) + (wm * 128 + (hm) * 64 + mb * 16 + l15) * 64;  \
    af[mb][0] = *(const bf16x8*)&rp_[((quad ^ sw7) * 8)];                 \
    af[mb][1] = *(const bf16x8*)&rp_[(((4 + quad) ^ sw7) * 8)];           \
  }
#define LOADB(dst, Bb, hn)                                                \
  _Pragma("unroll") for (int nq = 0; nq < 2; ++nq) {                      \
    const u16* rp_ = (Bb) + (wn * 64 + (hn) * 32 + nq * 16 + l15) * 64;   \
    dst[nq][0] = *(const bf16x8*)&rp_[((quad ^ sw7) * 8)];                \
    dst[nq][1] = *(const bf16x8*)&rp_[(((4 + quad) ^ sw7) * 8)];          \
  }
#define MFMAQ(bfh, hm, hn)                                                \
  _Pragma("unroll") for (int mb = 0; mb < 4; ++mb)                        \
  _Pragma("unroll") for (int nq = 0; nq < 2; ++nq) {                      \
    acc[(hm) * 4 + mb][(hn) * 2 + nq] =                                   \
        __builtin_amdgcn_mfma_f32_16x16x32_bf16(                          \
            af[mb][0], bfh[nq][0], acc[(hm) * 4 + mb][(hn) * 2 + nq], 0,  \
            0, 0);                                                        \
    acc[(hm) * 4 + mb][(hn) * 2 + nq] =                                   \
        __builtin_amdgcn_mfma_f32_16x16x32_bf16(                          \
            af[mb][1], bfh[nq][1], acc[(hm) * 4 + mb][(hn) * 2 + nq], 0,  \
            0, 0);                                                        \
  }

#pragma unroll 2
  for (int t = 0; t < 16; ++t) {
    const u16* Ac = ldsA + (t & 1) * 16384;
    const u16* Bc = ldsB + (t & 1) * 16384;
    const int nb1 = (t + 1) & 1;  // buf for tile t+1
    const int nb2 = t & 1;        // buf for tile t+2
    // ---- phase 0: reads UA_p0 + UB_p0 (12 ds_read_b128), stage UB_p1(t+1)
    LOADA(Ac, 0);
    LOADB(bf0, Bc, 0);
    if (t < 15) {
      STAGEU(pUB1a, pUB1b, ldsB, dB1, nb1);
      pUB1a += 64; pUB1b += 64;
    }
    __builtin_amdgcn_s_barrier();
    asm volatile("s_waitcnt lgkmcnt(0)" ::: "memory");
    __builtin_amdgcn_s_setprio(1);
    MFMAQ(bf0, 0, 0);
    __builtin_amdgcn_s_setprio(0);
    __builtin_amdgcn_s_barrier();
    // ---- phase 1: reads UB_p1, stage UA_p0(t+2) (last read p0, closed)
    LOADB(bf1, Bc, 1);
    if (t < 14) {
      STAGEU(pUA0a, pUA0b, ldsA, dA0, nb2);
      pUA0a += 64; pUA0b += 64;
    }
    __builtin_amdgcn_s_barrier();
    asm volatile("s_waitcnt lgkmcnt(0)" ::: "memory");
    __builtin_amdgcn_s_setprio(1);
    MFMAQ(bf1, 0, 1);
    __builtin_amdgcn_s_setprio(0);
    __builtin_amdgcn_s_barrier();
    // ---- phase 2: reads UA_p2, stage UB_p0(t+2) (last read p0, closed)
    LOADA(Ac, 1);
    if (t < 14) {
      STAGEU(pUB0a, pUB0b, ldsB, dB0, nb2);
      pUB0a += 64; pUB0b += 64;
    }
    __builtin_amdgcn_s_barrier();
    asm volatile("s_waitcnt lgkmcnt(0)" ::: "memory");
    __builtin_amdgcn_s_setprio(1);
    MFMAQ(bf0, 1, 0);
    __builtin_amdgcn_s_setprio(0);
    __builtin_amdgcn_s_barrier();
    // ---- phase 3: regs only, stage UA_p2(t+2) (last read p2, closed)
    if (t < 14) {
      STAGEU(pUA2a, pUA2b, ldsA, dA2, nb2);
      pUA2a += 64; pUA2b += 64;
    }
    __builtin_amdgcn_s_setprio(1);
    MFMAQ(bf1, 1, 1);
    __builtin_amdgcn_s_setprio(0);
    if (t < 14) {
      asm volatile("s_waitcnt vmcnt(6)" ::: "memory");
      __builtin_amdgcn_s_barrier();
    } else if (t == 14) {
      asm volatile("s_waitcnt vmcnt(0)" ::: "memory");
      __builtin_amdgcn_s_barrier();
    }
  }
#undef STAGEU
#undef LOADA
#undef LOADB
#undef MFMAQ

  if (wsel < 2) {
    const float qs = (wsel == 0) ? 0.125f * 1.44269504088896f : 1.0f;
    const int colb = n0 + wn * 64;
    const int h = colb >> 6;
    const float bias0 = bsel[colb + l15];
    const float bias1 = bsel[colb + 16 + l15];
    const float bias2 = bsel[colb + 32 + l15];
    const float bias3 = bsel[colb + 48 + l15];
#pragma unroll
    for (int mb = 0; mb < 8; ++mb)
#pragma unroll
      for (int r = 0; r < 4; ++r) {
        int m = m0 + wm * 128 + mb * 16 + quad * 4 + r;
        int b = m >> 11, s = m & (SS - 1);
        float2 t0 = tab[s * 32 + l15];
        float2 t1 = tab[s * 32 + 16 + l15];
        size_t obase = ((size_t)(b * NHH + h) * SS + s) * HDD;
        float x1 = acc[mb][0][r] + bias0;
        float x2 = acc[mb][2][r] + bias2;
        Osel[obase + l15] = f2bf((x1 * t0.x - x2 * t0.y) * qs);
        Osel[obase + 32 + l15] = f2bf((x2 * t0.x + x1 * t0.y) * qs);
        float y1 = acc[mb][1][r] + bias1;
        float y2 = acc[mb][3][r] + bias3;
        Osel[obase + 16 + l15] = f2bf((y1 * t1.x - y2 * t1.y) * qs);
        Osel[obase + 48 + l15] = f2bf((y2 * t1.x + y1 * t1.y) * qs);
      }
  } else {
#pragma unroll
    for (int nb = 0; nb < 4; ++nb) {
      int col = n0 + wn * 64 + nb * 16 + l15;
      int h = col >> 6, d = col & 63;
      float bias = bsel[col];
#pragma unroll
      for (int mb = 0; mb < 8; ++mb) {
        int m = m0 + wm * 128 + mb * 16 + quad * 4;
        int b = m >> 11, s = m & (SS - 1);
        uint2 w2;
        w2.x = pk_bf16(acc[mb][nb][0] + bias, acc[mb][nb][1] + bias);
        w2.y = pk_bf16(acc[mb][nb][2] + bias, acc[mb][nb][3] + bias);
        *(uint2*)&Osel[((size_t)((b * NHH + h) * HDD + d)) * SS + s] = w2;
      }
    }
  }
}

// ---------------------------------------------------------------------------
// Final projection GEMM v2: 128x128 tile, BK=64, 4 waves, double-buffered
// 64 KB LDS, depth-2 counted prefetch. (unchanged from R5 — verified, ~14 us)
// ---------------------------------------------------------------------------
__global__ __launch_bounds__(256) void gemm_out(const u16* __restrict__ X,
                                                const u16* __restrict__ W,
                                                float* __restrict__ Ofp) {
  __shared__ __align__(16) u16 As[2][8192];  // [buf][128*64]
  __shared__ __align__(16) u16 Bs[2][8192];
  const int tid = threadIdx.x;
  const int lane = tid & 63;
  const int wv = __builtin_amdgcn_readfirstlane(tid >> 6);
  const int l15 = lane & 15, quad = lane >> 4;
  const int sw7 = l15 & 7;
  const int wm = wv >> 1, wn = wv & 1;
  const int r8 = lane >> 3, c7 = lane & 7;

  int wg = blockIdx.x;
  int swz = (wg & 7) * 32 + (wg >> 3);  // 256 % 8 == 0: bijective
  const int n0 = (swz & 7) * 128;
  const int m0 = (swz >> 3) * 128;

  const int csw = (c7 ^ r8) * 8;
  const u16* gA = X + (size_t)(m0 + wv * 32 + r8) * HH + csw;
  const u16* gB = W + (size_t)(n0 + wv * 32 + r8) * HH + csw;
  u16* const dA = &As[0][0] + (wv * 32) * 64;
  u16* const dB = &Bs[0][0] + (wv * 32) * 64;

#define STG_O(tile, buf)                                           \
  _Pragma("unroll") for (int u = 0; u < 4; ++u) {                  \
    gload_lds16(gA + (size_t)u * 8 * HH + (tile) * 64,             \
                dA + (buf) * 8192 + u * 512);                      \
    gload_lds16(gB + (size_t)u * 8 * HH + (tile) * 64,             \
                dB + (buf) * 8192 + u * 512);                      \
  }

  floatx4 acc[4][4];
#pragma unroll
  for (int i = 0; i < 4; ++i)
#pragma unroll
    for (int j = 0; j < 4; ++j) acc[i][j] = (floatx4){0.f, 0.f, 0.f, 0.f};

  STG_O(0, 0);
  STG_O(1, 1);
  asm volatile("s_waitcnt vmcnt(8)" ::: "memory");
  __builtin_amdgcn_s_barrier();

  for (int t = 0; t < 16; ++t) {
    const u16* Ac = &As[0][0] + (t & 1) * 8192;
    const u16* Bc = &Bs[0][0] + (t & 1) * 8192;
    bf16x8 af[4][2], bfr[4][2];
#pragma unroll
    for (int mb = 0; mb < 4; ++mb) {
      const u16* rp = Ac + (wm * 64 + mb * 16 + l15) * 64;
      af[mb][0] = *(const bf16x8*)&rp[(quad ^ sw7) * 8];
      af[mb][1] = *(const bf16x8*)&rp[((4 + quad) ^ sw7) * 8];
    }
#pragma unroll
    for (int nb = 0; nb < 4; ++nb) {
      const u16* rp = Bc + (wn * 64 + nb * 16 + l15) * 64;
      bfr[nb][0] = *(const bf16x8*)&rp[(quad ^ sw7) * 8];
      bfr[nb][1] = *(const bf16x8*)&rp[((4 + quad) ^ sw7) * 8];
    }
    __builtin_amdgcn_s_barrier();  // all waves' reads of this buf issued
    if (t < 14) STG_O(t + 2, t & 1);
    asm volatile("s_waitcnt lgkmcnt(0)" ::: "memory");
    __builtin_amdgcn_sched_barrier(0);
    __builtin_amdgcn_s_setprio(1);
#pragma unroll
    for (int mb = 0; mb < 4; ++mb)
#pragma unroll
      for (int nb = 0; nb < 4; ++nb) {
        acc[mb][nb] = __builtin_amdgcn_mfma_f32_16x16x32_bf16(
            af[mb][0], bfr[nb][0], acc[mb][nb], 0, 0, 0);
        acc[mb][nb] = __builtin_amdgcn_mfma_f32_16x16x32_bf16(
            af[mb][1], bfr[nb][1], acc[mb][nb], 0, 0, 0);
      }
    __builtin_amdgcn_s_setprio(0);
    if (t < 14) {
      asm volatile("s_waitcnt vmcnt(8)" ::: "memory");
    } else if (t == 14) {
      asm volatile("s_waitcnt vmcnt(0)" ::: "memory");
    }
    __builtin_amdgcn_s_barrier();
  }
#undef STG_O

#pragma unroll
  for (int mb = 0; mb < 4; ++mb)
#pragma unroll
    for (int r = 0; r < 4; ++r) {
      int m = m0 + wm * 64 + mb * 16 + quad * 4 + r;
#pragma unroll
      for (int nb = 0; nb < 4; ++nb)
        Ofp[(size_t)m * HH + n0 + wn * 64 + nb * 16 + l15] = acc[mb][nb][r];
    }
}

// ---------------------------------------------------------------------------
// Flash attention, key-partitioned quadrant scheme.
// R9 == R8 resubmitted (R8's failure diagnosed as infra: R7 ran the same
// barrier structure; R8 only added a stricter wait, which cannot deadlock).
// Depth-2 K prefetch, 40 KB LDS, K triple-buffered (t+2 ahead), V double-
// buffered (t+1 ahead). End-of-tile: vmcnt(2)+lgkmcnt(0) + sched_barrier +
// s_barrier — counted vmcnt keeps K(t+2) in flight across the barrier (T4);
// lgkm drain closes R7's race (ds_reads queued past barrier, rule #18).
// ---------------------------------------------------------------------------
__global__ __launch_bounds__(256, 4) void attn_mfma(const u16* __restrict__ Qg,
                                                    const u16* __restrict__ Kg,
                                                    const u16* __restrict__ Vtg,
                                                    u16* __restrict__ A) {
  __shared__ __align__(16) u16 smem[20480];  // 40 KB
  float* const lpart = (float*)smem;        // [4][32]
  float* const Opart = (float*)smem + 128;  // [2][32][68]

  const int tid = threadIdx.x;
  const int lane = tid & 63;
  const int wv = __builtin_amdgcn_readfirstlane(tid >> 6);
  const int l15 = lane & 15, quad = lane >> 4;
  const int sw7 = l15 & 7;
  const int bh = blockIdx.x, qt = blockIdx.y;
  const size_t hb = (size_t)bh * SS * HDD;  // Q,K [bh][s][d]; Vt [bh][d][s]
  const int kh = wv >> 1;  // key-half
  const int qh = wv & 1;   // qrow-half

  u16* const Kb0 = smem;
  u16* const Kb1 = smem + 4096;
  u16* const Kb2 = smem + 8192;
  u16* const Vb0 = smem + 12288;
  u16* const Vb1 = smem + 16384;
  u16* Kbuf[3] = {Kb0, Kb1, Kb2};
  u16* Vbuf[2] = {Vb0, Vb1};

  // staging geometry: wave covers segs {wv*2, wv*2+1} of 8 rows each.
  const int r8 = lane >> 3, c7 = lane & 7;
  const int cs = (c7 ^ r8) * 8;  // XOR-swizzled chunk (u16 offset)
  const u16* const Kt = Kg + hb;
  const u16* const Vt = Vtg + hb;
  const int row0 = (wv * 2 + 0) * 8 + r8;
  const int row1 = (wv * 2 + 1) * 8 + r8;
  const int koff0 = row0 * HDD + cs;
  const int koff1 = row1 * HDD + cs;
  const int voff0 = row0 * SS + cs;
  const int voff1 = row1 * SS + cs;
  const int sd0 = (wv * 2 + 0) * 512;  // LDS dst offset within buffer
  const int sd1 = (wv * 2 + 1) * 512;

#define STG_K(tile, bp)                                  \
  do {                                                   \
    gload_lds16(Kt + (tile) * 4096 + koff0, (bp) + sd0); \
    gload_lds16(Kt + (tile) * 4096 + koff1, (bp) + sd1); \
  } while (0)
#define STG_V(tile, bp)                                  \
  do {                                                   \
    gload_lds16(Vt + (tile) * 64 + voff0, (bp) + sd0);   \
    gload_lds16(Vt + (tile) * 64 + voff1, (bp) + sd1);   \
  } while (0)

  // prologue: Q->K[2], K0->K[0], V0->V[0], K1->K[1]  (8 loads, this order)
  gload_lds16(Qg + hb + qt * 4096 + koff0, Kb2 + sd0);
  gload_lds16(Qg + hb + qt * 4096 + koff1, Kb2 + sd1);
  STG_K(0, Kb0);
  STG_V(0, Vb0);
  STG_K(1, Kb1);
  asm volatile("s_waitcnt vmcnt(2)" ::: "memory");  // Q,K0,V0 landed; K1 fly
  __builtin_amdgcn_s_barrier();

  // Q B-frags (loop-invariant) from K[2]: qrows qh*32 + nb*16 + l15
  bf16x8 qf[2][2];
#pragma unroll
  for (int nb = 0; nb < 2; ++nb)
#pragma unroll
    for (int h2 = 0; h2 < 2; ++h2)
      qf[nb][h2] = *(const bf16x8*)&Kb2[(qh * 32 + nb * 16 + l15) * 64 +
                                        (((h2 * 4 + quad) ^ sw7) * 8)];
  asm volatile("s_waitcnt lgkmcnt(0)" ::: "memory");  // qf reads complete
  __builtin_amdgcn_sched_barrier(0);
  __builtin_amdgcn_s_barrier();  // before K(2) overwrites K[2] at iter 0

  float l_acc[2] = {0.f, 0.f};
  floatx4 o[4][2];
#pragma unroll
  for (int dmb = 0; dmb < 4; ++dmb)
#pragma unroll
    for (int nb = 0; nb < 2; ++nb) o[dmb][nb] = (floatx4){0.f, 0.f, 0.f, 0.f};

  // one key-tile compute, statically-addressed buffers
  auto tile_compute = [&](const u16* ks, const u16* vs) {
    // S^T quadrant: keys kh*32+kmb*16+quad*4+r, qrows qh*32+nb*16+l15
    floatx4 st[2][2];
    __builtin_amdgcn_s_setprio(1);
#pragma unroll
    for (int kmb = 0; kmb < 2; ++kmb) {
      int krow = kh * 32 + kmb * 16 + l15;
      bf16x8 ak0 = *(const bf16x8*)&ks[krow * 64 + ((quad ^ sw7) * 8)];
      bf16x8 ak1 = *(const bf16x8*)&ks[krow * 64 + (((4 + quad) ^ sw7) * 8)];
#pragma unroll
      for (int nb = 0; nb < 2; ++nb) {
        floatx4 z = (floatx4){0.f, 0.f, 0.f, 0.f};
        z = __builtin_amdgcn_mfma_f32_16x16x32_bf16(ak0, qf[nb][0], z, 0, 0, 0);
        z = __builtin_amdgcn_mfma_f32_16x16x32_bf16(ak1, qf[nb][1], z, 0, 0, 0);
        st[kmb][nb] = z;
      }
    }
    __builtin_amdgcn_s_setprio(0);

    // exp2 + pack P into MFMA-B layout (permutation trick, in-register).
    bf16x8 bp[2];
#pragma unroll
    for (int nb = 0; nb < 2; ++nb) {
      float p00 = __builtin_amdgcn_exp2f(st[0][nb][0]);
      float p01 = __builtin_amdgcn_exp2f(st[0][nb][1]);
      float p02 = __builtin_amdgcn_exp2f(st[0][nb][2]);
      float p03 = __builtin_amdgcn_exp2f(st[0][nb][3]);
      float p10 = __builtin_amdgcn_exp2f(st[1][nb][0]);
      float p11 = __builtin_amdgcn_exp2f(st[1][nb][1]);
      float p12 = __builtin_amdgcn_exp2f(st[1][nb][2]);
      float p13 = __builtin_amdgcn_exp2f(st[1][nb][3]);
      l_acc[nb] += ((p00 + p01) + (p02 + p03)) + ((p10 + p11) + (p12 + p13));
      union { bf16x8 v; unsigned u[4]; } pu;
      pu.u[0] = pk_asm(p00, p01);
      pu.u[1] = pk_asm(p02, p03);
      pu.u[2] = pk_asm(p10, p11);
      pu.u[3] = pk_asm(p12, p13);
      bp[nb] = pu.v;
    }

    // O^T += V^T(perm) . P(perm): A elem j = Vt[d][kh*32+(j>>2)*16+quad*4+(j&3)]
    const int cb0 = kh * 4 + (quad >> 1);
    const int cb1 = cb0 + 2;
    const int sub = (quad & 1) * 4;
    __builtin_amdgcn_s_setprio(1);
#pragma unroll
    for (int dmb = 0; dmb < 4; ++dmb) {
      int vr = (dmb * 16 + l15) * 64;
      union { bf16x8 v; uint2 d2[2]; } au;
      au.d2[0] = *(const uint2*)&vs[vr + ((cb0 ^ sw7) * 8) + sub];
      au.d2[1] = *(const uint2*)&vs[vr + ((cb1 ^ sw7) * 8) + sub];
#pragma unroll
      for (int nb = 0; nb < 2; ++nb)
        o[dmb][nb] = __builtin_amdgcn_mfma_f32_16x16x32_bf16(au.v, bp[nb],
                                                             o[dmb][nb], 0, 0, 0);
    }
    __builtin_amdgcn_s_setprio(0);
  };

  // steady-state tile: stage V(t+1), K(t+2); compute t; then drain the
  // wave's LDS queue (lgkmcnt 0) + counted vmcnt(2); sched_barrier pins
  // MFMAs above the wait (rule #18); barrier.
#define ATILE(t, i)                                                       \
  do {                                                                    \
    STG_V((t) + 1, Vbuf[((i) + 1) & 1]);                                  \
    STG_K((t) + 2, Kbuf[((i) + 2) % 3]);                                  \
    tile_compute(Kbuf[(i) % 3], Vbuf[(i) & 1]);                           \
    asm volatile("s_waitcnt vmcnt(2) lgkmcnt(0)" ::: "memory");           \
    __builtin_amdgcn_sched_barrier(0);                                    \
    __builtin_amdgcn_s_barrier();                                         \
  } while (0)

  for (int tb = 0; tb < 30; tb += 6) {
    ATILE(tb + 0, 0);
    ATILE(tb + 1, 1);
    ATILE(tb + 2, 2);
    ATILE(tb + 3, 3);
    ATILE(tb + 4, 4);
    ATILE(tb + 5, 5);
  }
  // t = 30 (30 % 3 == 0, 30 & 1 == 0): stage V(31) only
  STG_V(31, Vb1);
  tile_compute(Kb0, Vb0);
  asm volatile("s_waitcnt vmcnt(0) lgkmcnt(0)" ::: "memory");
  __builtin_amdgcn_sched_barrier(0);
  __builtin_amdgcn_s_barrier();
  // t = 31 (31 % 3 == 1, 31 & 1 == 1)
  tile_compute(Kb1, Vb1);
#undef ATILE
#undef STG_K
#undef STG_V

  // ---- epilogue: combine key-halves ----
  // l: reduce over quads (16 keys of this wave), publish per-wave partial
#pragma unroll
  for (int nb = 0; nb < 2; ++nb) {
    l_acc[nb] += __shfl_xor(l_acc[nb], 16);
    l_acc[nb] += __shfl_xor(l_acc[nb], 32);
  }
  __syncthreads();  // all compute reads done before lpart/Opart overwrite
  if (quad == 0) {
    lpart[wv * 32 + l15] = l_acc[0];
    lpart[wv * 32 + 16 + l15] = l_acc[1];
  }
  // O: waves kh==1 publish partial (qrow-major rows of 68 fp32)
  if (kh == 1) {
    float* dst = Opart + qh * (32 * 68);
#pragma unroll
    for (int nb = 0; nb < 2; ++nb)
#pragma unroll
      for (int dmb = 0; dmb < 4; ++dmb)
        *(floatx4*)&dst[(nb * 16 + l15) * 68 + dmb * 16 + quad * 4] =
            o[dmb][nb];
  }
  __syncthreads();
  if (kh == 0) {
    const int b = bh >> 4, h = bh & 15;
    const float* src = Opart + qh * (32 * 68);
    float inv[2];
#pragma unroll
    for (int nb = 0; nb < 2; ++nb)
      inv[nb] = 1.f / (lpart[wv * 32 + nb * 16 + l15] +
                       lpart[(wv + 2) * 32 + nb * 16 + l15]);
#pragma unroll
    for (int nb = 0; nb < 2; ++nb) {
      int s = qt * 64 + qh * 32 + nb * 16 + l15;
#pragma unroll
      for (int dmb = 0; dmb < 4; ++dmb) {
        floatx4 part =
            *(const floatx4*)&src[(nb * 16 + l15) * 68 + dmb * 16 + quad * 4];
        floatx4 tot = (o[dmb][nb] + part) * inv[nb];
        uint2 w2;
        w2.x = pk_asm(tot[0], tot[1]);
        w2.y = pk_asm(tot[2], tot[3]);
        *(uint2*)&A[((size_t)(b * SS + s) * HH) + h * HDD + dmb * 16 +
                    quad * 4] = w2;
      }
    }
  }
}

// ---------------------------------------------------------------------------
extern "C" void kernel_launch(void* const* d_in, const int* in_sizes, int n_in,
                              void* d_out, int out_size, void* d_ws,
                              size_t ws_size, hipStream_t stream) {
  const float* hs = (const float*)d_in[0];
  const int* pos = (const int*)d_in[1];
  const float* Wq = (const float*)d_in[2];
  const float* bq = (const float*)d_in[3];
  const float* Wk = (const float*)d_in[4];
  const float* bk = (const float*)d_in[5];
  const float* Wv = (const float*)d_in[6];
  const float* bv = (const float*)d_in[7];
  const float* Wo = (const float*)d_in[8];
  float* out = (float*)d_out;

  u16* hs_b = (u16*)d_ws;      // 4M
  u16* wq_b = hs_b + 4194304;  // 1M each
  u16* wk_b = wq_b + 1048576;
  u16* wv_b = wk_b + 1048576;
  u16* wo_b = wv_b + 1048576;
  u16* Qb = wo_b + 1048576;    // 4M each
  u16* Kb = Qb + 4194304;
  u16* Vtb = Kb + 4194304;     // transposed V [bh][d][s]
  u16* Ab = Vtb + 4194304;
  float2* tab = (float2*)(Ab + 4194304);  // [2048][32] cos/sin

  hipLaunchKernelGGL(convert_bf, dim3(8448), dim3(256), 0, stream, hs, Wq, Wk,
                     Wv, Wo, pos, hs_b, wq_b, wk_b, wv_b, wo_b, tab);
  hipLaunchKernelGGL(mfma_gemm_qkv, dim3(192), dim3(512), 0, stream, hs_b,
                     wq_b, wk_b, wv_b, bq, bk, bv, tab, Qb, Kb, Vtb);
  hipLaunchKernelGGL(attn_mfma, dim3(32, 32), dim3(256), 0, stream, Qb, Kb,
                     Vtb, Ab);
  hipLaunchKernelGGL(gemm_out, dim3(256), dim3(256), 0, stream, Ab, wo_b,
                     out);
}

// Round 10
// 182.024 us; speedup vs baseline: 1.1506x; 1.1506x over previous
//
#include <hip/hip_runtime.h>
#include <hip/hip_bf16.h>
#include <math.h>

#define SS 2048
#define HH 1024
#define NHH 16
#define HDD 64
#define BH 32
#define MM 4096

typedef unsigned short u16;
using bf16x8 = __attribute__((ext_vector_type(8))) short;
using floatx4 = __attribute__((ext_vector_type(4))) float;

__device__ __forceinline__ u16 f2bf(float f) {
  unsigned u = __float_as_uint(f);
  u += 0x7fffu + ((u >> 16) & 1u);
  return (u16)(u >> 16);
}
__device__ __forceinline__ unsigned pk_bf16(float a, float b) {
  union { __hip_bfloat162 h2; unsigned u; } c;
  c.h2 = __float22bfloat162_rn(float2{a, b});
  return c.u;
}
// single-instruction packed f32->bf16 (RNE). No builtin on gfx950 (m240).
__device__ __forceinline__ unsigned pk_asm(float a, float b) {
  unsigned r;
  asm("v_cvt_pk_bf16_f32 %0, %1, %2" : "=v"(r) : "v"(a), "v"(b));
  return r;
}
__device__ __forceinline__ void gload_lds16(const u16* g, u16* l) {
  __builtin_amdgcn_global_load_lds(
      (const __attribute__((address_space(1))) void*)g,
      (__attribute__((address_space(3))) void*)l, 16, 0, 0);
}

// ---------------------------------------------------------------------------
// fp32 -> bf16 conversion (hs + 4 weights) + RoPE cos/sin table.
// ---------------------------------------------------------------------------
__global__ __launch_bounds__(256) void convert_bf(
    const float* __restrict__ hs, const float* __restrict__ wq,
    const float* __restrict__ wk, const float* __restrict__ wv,
    const float* __restrict__ wo, const int* __restrict__ pos,
    u16* __restrict__ hs_b, u16* __restrict__ wq_b, u16* __restrict__ wk_b,
    u16* __restrict__ wv_b, u16* __restrict__ wo_b,
    float2* __restrict__ tab) {
  int g = blockIdx.x * 256 + threadIdx.x;
  if (g < 2097152) {
    const float* src;
    u16* dst;
    int off;
    if (g < 1048576) {
      src = hs; dst = hs_b; off = g;
    } else {
      int t = g - 1048576;
      int w = t >> 18;
      off = t & 262143;
      src = (w == 0) ? wq : (w == 1) ? wk : (w == 2) ? wv : wo;
      dst = (w == 0) ? wq_b : (w == 1) ? wk_b : (w == 2) ? wv_b : wo_b;
    }
    float4 v = ((const float4*)src)[off];
    ushort4 o = make_ushort4(f2bf(v.x), f2bf(v.y), f2bf(v.z), f2bf(v.w));
    ((ushort4*)dst)[off] = o;
  } else {
    int idx = g - 2097152;  // 0..65535
    int s = idx >> 5, j = idx & 31;
    float p = (float)pos[s];
    const float c0 = 13.287712379549449f / 32.0f;  // log2(10000)/32
    float f = p * exp2f(-(float)j * c0);
    float sn, cs;
    sincosf(f, &sn, &cs);
    tab[idx] = float2{cs, sn};
  }
}

// ---------------------------------------------------------------------------
// QKV GEMM, 8-phase 256x256 schedule (T2+T3+T4+T5), BK=64, 8 waves (2Mx4N),
// 128 KB STATIC LDS double-buffer, counted vmcnt(6) once per K-tile.
// (unchanged from R3 — verified correct; ~44 us, limited by 192/256 CU fill)
// ---------------------------------------------------------------------------
__global__ __launch_bounds__(512, 2) void mfma_gemm_qkv(
    const u16* __restrict__ X, const u16* __restrict__ W0,
    const u16* __restrict__ W1, const u16* __restrict__ W2,
    const float* __restrict__ b0, const float* __restrict__ b1,
    const float* __restrict__ b2, const float2* __restrict__ tab,
    u16* __restrict__ O0, u16* __restrict__ O1, u16* __restrict__ O2) {
  __shared__ __align__(16) u16 lds[65536];  // 128 KB static
  const int tid = threadIdx.x;
  const int lane = tid & 63;
  const int wv = __builtin_amdgcn_readfirstlane(tid >> 6);
  const int l15 = lane & 15, quad = lane >> 4;
  const int sw7 = l15 & 7;
  const int wm = wv >> 2, wn = wv & 3;
  const int r8 = lane >> 3, c7 = lane & 7;

  // XCD-aware bijective swizzle: XCD x gets 24 contiguous (by,bx) tiles.
  int wg = blockIdx.x;
  int swz = (wg & 7) * 24 + (wg >> 3);
  int bx = swz % 12, by = swz / 12;
  const int m0 = by * 256;
  const int n0g = bx * 256;
  const int wsel = n0g >> 10;
  const int n0 = n0g & 1023;
  const u16* Wsel = (wsel == 1) ? W1 : (wsel == 2) ? W2 : W0;
  const float* bsel = (wsel == 1) ? b1 : (wsel == 2) ? b2 : b0;
  u16* Osel = (wsel == 1) ? O1 : (wsel == 2) ? O2 : O0;

  u16* const ldsA = lds;            // [buf][256][64] u16
  u16* const ldsB = lds + 32768;

  // per-unit global sources (2 gloads each), pre-swizzled chunk c7^r8
  const int csw = (c7 ^ r8) * 8;
  const int rA0 = (wv >> 2) * 128 + (wv & 3) * 16;  // UA_p0 per-wave base row
  const int rB0 = (wv >> 1) * 64 + (wv & 1) * 16;   // UB_p0 per-wave base row
  const u16* gA0a = X + (size_t)(m0 + rA0 + r8) * HH + csw;
  const u16* gA0b = gA0a + 8 * HH;
  const u16* gA2a = gA0a + 64 * HH;
  const u16* gA2b = gA0a + 72 * HH;
  const u16* gB0a = Wsel + (size_t)(n0 + rB0 + r8) * HH + csw;
  const u16* gB0b = gB0a + 8 * HH;
  const u16* gB1a = gB0a + 32 * HH;
  const u16* gB1b = gB0a + 40 * HH;
  // LDS dst offsets (u16), within buf (buf stride 16384)
  const int dA0 = rA0 * 64;
  const int dA2 = dA0 + 4096;   // +64 rows
  const int dB0 = rB0 * 64;
  const int dB1 = dB0 + 2048;   // +32 rows

#define STAGEU(pa, pb, base, doff, buf)                  \
  do {                                                   \
    u16* d_ = (base) + (buf) * 16384 + (doff);           \
    gload_lds16((pa), d_);                               \
    gload_lds16((pb), d_ + 512);                         \
  } while (0)

  floatx4 acc[8][4];
#pragma unroll
  for (int i = 0; i < 8; ++i)
#pragma unroll
    for (int j = 0; j < 4; ++j) acc[i][j] = (floatx4){0.f, 0.f, 0.f, 0.f};

  // prologue: tile0 all 4 units, tile1 {UA_p0, UB_p0, UA_p2} (7 units);
  // UB_p1(1) arrives at t0/p0. vmcnt(6) -> tile0 landed, tile1's 3 in flight.
  STAGEU(gA0a, gA0b, ldsA, dA0, 0);
  STAGEU(gA2a, gA2b, ldsA, dA2, 0);
  STAGEU(gB0a, gB0b, ldsB, dB0, 0);
  STAGEU(gB1a, gB1b, ldsB, dB1, 0);
  STAGEU(gA0a + 64, gA0b + 64, ldsA, dA0, 1);
  STAGEU(gB0a + 64, gB0b + 64, ldsB, dB0, 1);
  STAGEU(gA2a + 64, gA2b + 64, ldsA, dA2, 1);
  asm volatile("s_waitcnt vmcnt(6)" ::: "memory");
  __builtin_amdgcn_s_barrier();

  // running prefetch pointers (u16 offsets advance 64 per tile)
  const u16 *pUB1a = gB1a + 64, *pUB1b = gB1b + 64;      // next target: tile 1
  const u16 *pUA0a = gA0a + 128, *pUA0b = gA0b + 128;    // next target: tile 2
  const u16 *pUB0a = gB0a + 128, *pUB0b = gB0b + 128;
  const u16 *pUA2a = gA2a + 128, *pUA2b = gA2b + 128;

  bf16x8 af[4][2], bf0[2][2], bf1[2][2];

#define LOADA(Ab, hm)                                                     \
  _Pragma("unroll") for (int mb = 0; mb < 4; ++mb) {                      \
    const u16* rp_ = (Ab) + (wm * 128 + (hm) * 64 + mb * 16 + l15) * 64;  \
    af[mb][0] = *(const bf16x8*)&rp_[((quad ^ sw7) * 8)];                 \
    af[mb][1] = *(const bf16x8*)&rp_[(((4 + quad) ^ sw7) * 8)];           \
  }
#define LOADB(dst, Bb, hn)                                                \
  _Pragma("unroll") for (int nq = 0; nq < 2; ++nq) {                      \
    const u16* rp_ = (Bb) + (wn * 64 + (hn) * 32 + nq * 16 + l15) * 64;   \
    dst[nq][0] = *(const bf16x8*)&rp_[((quad ^ sw7) * 8)];                \
    dst[nq][1] = *(const bf16x8*)&rp_[(((4 + quad) ^ sw7) * 8)];          \
  }
#define MFMAQ(bfh, hm, hn)                                                \
  _Pragma("unroll") for (int mb = 0; mb < 4; ++mb)                        \
  _Pragma("unroll") for (int nq = 0; nq < 2; ++nq) {                      \
    acc[(hm) * 4 + mb][(hn) * 2 + nq] =                                   \
        __builtin_amdgcn_mfma_f32_16x16x32_bf16(                          \
            af[mb][0], bfh[nq][0], acc[(hm) * 4 + mb][(hn) * 2 + nq], 0,  \
            0, 0);                                                        \
    acc[(hm) * 4 + mb][(hn) * 2 + nq] =                                   \
        __builtin_amdgcn_mfma_f32_16x16x32_bf16(                          \
            af[mb][1], bfh[nq][1], acc[(hm) * 4 + mb][(hn) * 2 + nq], 0,  \
            0, 0);                                                        \
  }

#pragma unroll 2
  for (int t = 0; t < 16; ++t) {
    const u16* Ac = ldsA + (t & 1) * 16384;
    const u16* Bc = ldsB + (t & 1) * 16384;
    const int nb1 = (t + 1) & 1;  // buf for tile t+1
    const int nb2 = t & 1;        // buf for tile t+2
    // ---- phase 0: reads UA_p0 + UB_p0 (12 ds_read_b128), stage UB_p1(t+1)
    LOADA(Ac, 0);
    LOADB(bf0, Bc, 0);
    if (t < 15) {
      STAGEU(pUB1a, pUB1b, ldsB, dB1, nb1);
      pUB1a += 64; pUB1b += 64;
    }
    __builtin_amdgcn_s_barrier();
    asm volatile("s_waitcnt lgkmcnt(0)" ::: "memory");
    __builtin_amdgcn_s_setprio(1);
    MFMAQ(bf0, 0, 0);
    __builtin_amdgcn_s_setprio(0);
    __builtin_amdgcn_s_barrier();
    // ---- phase 1: reads UB_p1, stage UA_p0(t+2) (last read p0, closed)
    LOADB(bf1, Bc, 1);
    if (t < 14) {
      STAGEU(pUA0a, pUA0b, ldsA, dA0, nb2);
      pUA0a += 64; pUA0b += 64;
    }
    __builtin_amdgcn_s_barrier();
    asm volatile("s_waitcnt lgkmcnt(0)" ::: "memory");
    __builtin_amdgcn_s_setprio(1);
    MFMAQ(bf1, 0, 1);
    __builtin_amdgcn_s_setprio(0);
    __builtin_amdgcn_s_barrier();
    // ---- phase 2: reads UA_p2, stage UB_p0(t+2) (last read p0, closed)
    LOADA(Ac, 1);
    if (t < 14) {
      STAGEU(pUB0a, pUB0b, ldsB, dB0, nb2);
      pUB0a += 64; pUB0b += 64;
    }
    __builtin_amdgcn_s_barrier();
    asm volatile("s_waitcnt lgkmcnt(0)" ::: "memory");
    __builtin_amdgcn_s_setprio(1);
    MFMAQ(bf0, 1, 0);
    __builtin_amdgcn_s_setprio(0);
    __builtin_amdgcn_s_barrier();
    // ---- phase 3: regs only, stage UA_p2(t+2) (last read p2, closed)
    if (t < 14) {
      STAGEU(pUA2a, pUA2b, ldsA, dA2, nb2);
      pUA2a += 64; pUA2b += 64;
    }
    __builtin_amdgcn_s_setprio(1);
    MFMAQ(bf1, 1, 1);
    __builtin_amdgcn_s_setprio(0);
    if (t < 14) {
      asm volatile("s_waitcnt vmcnt(6)" ::: "memory");
      __builtin_amdgcn_s_barrier();
    } else if (t == 14) {
      asm volatile("s_waitcnt vmcnt(0)" ::: "memory");
      __builtin_amdgcn_s_barrier();
    }
  }
#undef STAGEU
#undef LOADA
#undef LOADB
#undef MFMAQ

  if (wsel < 2) {
    const float qs = (wsel == 0) ? 0.125f * 1.44269504088896f : 1.0f;
    const int colb = n0 + wn * 64;
    const int h = colb >> 6;
    const float bias0 = bsel[colb + l15];
    const float bias1 = bsel[colb + 16 + l15];
    const float bias2 = bsel[colb + 32 + l15];
    const float bias3 = bsel[colb + 48 + l15];
#pragma unroll
    for (int mb = 0; mb < 8; ++mb)
#pragma unroll
      for (int r = 0; r < 4; ++r) {
        int m = m0 + wm * 128 + mb * 16 + quad * 4 + r;
        int b = m >> 11, s = m & (SS - 1);
        float2 t0 = tab[s * 32 + l15];
        float2 t1 = tab[s * 32 + 16 + l15];
        size_t obase = ((size_t)(b * NHH + h) * SS + s) * HDD;
        float x1 = acc[mb][0][r] + bias0;
        float x2 = acc[mb][2][r] + bias2;
        Osel[obase + l15] = f2bf((x1 * t0.x - x2 * t0.y) * qs);
        Osel[obase + 32 + l15] = f2bf((x2 * t0.x + x1 * t0.y) * qs);
        float y1 = acc[mb][1][r] + bias1;
        float y2 = acc[mb][3][r] + bias3;
        Osel[obase + 16 + l15] = f2bf((y1 * t1.x - y2 * t1.y) * qs);
        Osel[obase + 48 + l15] = f2bf((y2 * t1.x + y1 * t1.y) * qs);
      }
  } else {
#pragma unroll
    for (int nb = 0; nb < 4; ++nb) {
      int col = n0 + wn * 64 + nb * 16 + l15;
      int h = col >> 6, d = col & 63;
      float bias = bsel[col];
#pragma unroll
      for (int mb = 0; mb < 8; ++mb) {
        int m = m0 + wm * 128 + mb * 16 + quad * 4;
        int b = m >> 11, s = m & (SS - 1);
        uint2 w2;
        w2.x = pk_bf16(acc[mb][nb][0] + bias, acc[mb][nb][1] + bias);
        w2.y = pk_bf16(acc[mb][nb][2] + bias, acc[mb][nb][3] + bias);
        *(uint2*)&Osel[((size_t)((b * NHH + h) * HDD + d)) * SS + s] = w2;
      }
    }
  }
}

// ---------------------------------------------------------------------------
// Final projection GEMM v2: 128x128 tile, BK=64, 4 waves, double-buffered
// 64 KB LDS, depth-2 counted prefetch. (unchanged from R5 — verified, ~14 us)
// ---------------------------------------------------------------------------
__global__ __launch_bounds__(256) void gemm_out(const u16* __restrict__ X,
                                                const u16* __restrict__ W,
                                                float* __restrict__ Ofp) {
  __shared__ __align__(16) u16 As[2][8192];  // [buf][128*64]
  __shared__ __align__(16) u16 Bs[2][8192];
  const int tid = threadIdx.x;
  const int lane = tid & 63;
  const int wv = __builtin_amdgcn_readfirstlane(tid >> 6);
  const int l15 = lane & 15, quad = lane >> 4;
  const int sw7 = l15 & 7;
  const int wm = wv >> 1, wn = wv & 1;
  const int r8 = lane >> 3, c7 = lane & 7;

  int wg = blockIdx.x;
  int swz = (wg & 7) * 32 + (wg >> 3);  // 256 % 8 == 0: bijective
  const int n0 = (swz & 7) * 128;
  const int m0 = (swz >> 3) * 128;

  const int csw = (c7 ^ r8) * 8;
  const u16* gA = X + (size_t)(m0 + wv * 32 + r8) * HH + csw;
  const u16* gB = W + (size_t)(n0 + wv * 32 + r8) * HH + csw;
  u16* const dA = &As[0][0] + (wv * 32) * 64;
  u16* const dB = &Bs[0][0] + (wv * 32) * 64;

#define STG_O(tile, buf)                                           \
  _Pragma("unroll") for (int u = 0; u < 4; ++u) {                  \
    gload_lds16(gA + (size_t)u * 8 * HH + (tile) * 64,             \
                dA + (buf) * 8192 + u * 512);                      \
    gload_lds16(gB + (size_t)u * 8 * HH + (tile) * 64,             \
                dB + (buf) * 8192 + u * 512);                      \
  }

  floatx4 acc[4][4];
#pragma unroll
  for (int i = 0; i < 4; ++i)
#pragma unroll
    for (int j = 0; j < 4; ++j) acc[i][j] = (floatx4){0.f, 0.f, 0.f, 0.f};

  STG_O(0, 0);
  STG_O(1, 1);
  asm volatile("s_waitcnt vmcnt(8)" ::: "memory");
  __builtin_amdgcn_s_barrier();

  for (int t = 0; t < 16; ++t) {
    const u16* Ac = &As[0][0] + (t & 1) * 8192;
    const u16* Bc = &Bs[0][0] + (t & 1) * 8192;
    bf16x8 af[4][2], bfr[4][2];
#pragma unroll
    for (int mb = 0; mb < 4; ++mb) {
      const u16* rp = Ac + (wm * 64 + mb * 16 + l15) * 64;
      af[mb][0] = *(const bf16x8*)&rp[(quad ^ sw7) * 8];
      af[mb][1] = *(const bf16x8*)&rp[((4 + quad) ^ sw7) * 8];
    }
#pragma unroll
    for (int nb = 0; nb < 4; ++nb) {
      const u16* rp = Bc + (wn * 64 + nb * 16 + l15) * 64;
      bfr[nb][0] = *(const bf16x8*)&rp[(quad ^ sw7) * 8];
      bfr[nb][1] = *(const bf16x8*)&rp[((4 + quad) ^ sw7) * 8];
    }
    __builtin_amdgcn_s_barrier();  // all waves' reads of this buf issued
    if (t < 14) STG_O(t + 2, t & 1);
    asm volatile("s_waitcnt lgkmcnt(0)" ::: "memory");
    __builtin_amdgcn_sched_barrier(0);
    __builtin_amdgcn_s_setprio(1);
#pragma unroll
    for (int mb = 0; mb < 4; ++mb)
#pragma unroll
      for (int nb = 0; nb < 4; ++nb) {
        acc[mb][nb] = __builtin_amdgcn_mfma_f32_16x16x32_bf16(
            af[mb][0], bfr[nb][0], acc[mb][nb], 0, 0, 0);
        acc[mb][nb] = __builtin_amdgcn_mfma_f32_16x16x32_bf16(
            af[mb][1], bfr[nb][1], acc[mb][nb], 0, 0, 0);
      }
    __builtin_amdgcn_s_setprio(0);
    if (t < 14) {
      asm volatile("s_waitcnt vmcnt(8)" ::: "memory");
    } else if (t == 14) {
      asm volatile("s_waitcnt vmcnt(0)" ::: "memory");
    }
    __builtin_amdgcn_s_barrier();
  }
#undef STG_O

#pragma unroll
  for (int mb = 0; mb < 4; ++mb)
#pragma unroll
    for (int r = 0; r < 4; ++r) {
      int m = m0 + wm * 64 + mb * 16 + quad * 4 + r;
#pragma unroll
      for (int nb = 0; nb < 4; ++nb)
        Ofp[(size_t)m * HH + n0 + wn * 64 + nb * 16 + l15] = acc[mb][nb][r];
    }
}

// ---------------------------------------------------------------------------
// Flash attention, key-partitioned quadrant scheme (reverted to verified R5:
// raw v_exp_f32, v_cvt_pk_bf16_f32 asm, uniform-base staging, setprio on
// MFMA clusters, 32 KB LDS dbuf with __syncthreads). The R6-R9 depth-2
// counted-vmcnt line is dead: it induced ~16 B/thread/tile scratch traffic
// (WRITE_SIZE 8->121 MB, FETCH 12->45 MB) and cost +69% attn time.
// ---------------------------------------------------------------------------
__global__ __launch_bounds__(256, 4) void attn_mfma(const u16* __restrict__ Qg,
                                                    const u16* __restrict__ Kg,
                                                    const u16* __restrict__ Vtg,
                                                    u16* __restrict__ A) {
  __shared__ __align__(16) u16 smem[16384];  // 32 KB
  u16* const Ks0 = smem;
  u16* const Ks1 = smem + 4096;
  u16* const Vs0 = smem + 8192;
  u16* const Vs1 = smem + 12288;
  float* const lpart = (float*)smem;        // [4][32]
  float* const Opart = (float*)smem + 128;  // [2][32][68]

  const int tid = threadIdx.x;
  const int lane = tid & 63;
  const int wv = __builtin_amdgcn_readfirstlane(tid >> 6);
  const int l15 = lane & 15, quad = lane >> 4;
  const int sw7 = l15 & 7;
  const int bh = blockIdx.x, qt = blockIdx.y;
  const size_t hb = (size_t)bh * SS * HDD;  // Q,K [bh][s][d]; Vt [bh][d][s]
  const int kh = wv >> 1;  // key-half
  const int qh = wv & 1;   // qrow-half

  // staging geometry: wave covers segs {wv*2, wv*2+1} of 8 rows each.
  // uniform bases + loop-invariant per-lane offsets (scalar tile advance).
  const int r8 = lane >> 3, c7 = lane & 7;
  const int cs = (c7 ^ r8) * 8;  // XOR-swizzled chunk (u16 offset)
  const u16* const Kt = Kg + hb;
  const u16* const Vt = Vtg + hb;
  const int row0 = (wv * 2 + 0) * 8 + r8;
  const int row1 = (wv * 2 + 1) * 8 + r8;
  const int koff0 = row0 * HDD + cs;
  const int koff1 = row1 * HDD + cs;
  const int voff0 = row0 * SS + cs;
  const int voff1 = row1 * SS + cs;
  u16* const kd0 = smem + (wv * 2 + 0) * 512;  // LDS dst (buf-relative)
  u16* const kd1 = smem + (wv * 2 + 1) * 512;

  // stage Q (64x64) into Ks1 + first K/V tile into buf0
  gload_lds16(Qg + hb + qt * 4096 + koff0, kd0 + 4096);
  gload_lds16(Qg + hb + qt * 4096 + koff1, kd1 + 4096);
  gload_lds16(Kt + koff0, kd0);
  gload_lds16(Kt + koff1, kd1);
  gload_lds16(Vt + voff0, kd0 + 8192);
  gload_lds16(Vt + voff1, kd1 + 8192);
  __syncthreads();

  // Q B-frags (loop-invariant): qrows qh*32 + nb*16 + l15
  bf16x8 qf[2][2];
#pragma unroll
  for (int nb = 0; nb < 2; ++nb)
#pragma unroll
    for (int h2 = 0; h2 < 2; ++h2)
      qf[nb][h2] = *(const bf16x8*)&Ks1[(qh * 32 + nb * 16 + l15) * 64 +
                                        (((h2 * 4 + quad) ^ sw7) * 8)];
  __syncthreads();  // qf reads complete before t=1 staging overwrites Ks1

  float l_acc[2] = {0.f, 0.f};
  floatx4 o[4][2];
#pragma unroll
  for (int dmb = 0; dmb < 4; ++dmb)
#pragma unroll
    for (int nb = 0; nb < 2; ++nb) o[dmb][nb] = (floatx4){0.f, 0.f, 0.f, 0.f};

  // one key-tile compute, statically-addressed buffers
  auto tile_compute = [&](const u16* ks, const u16* vs) {
    // S^T quadrant: keys kh*32+kmb*16+quad*4+r, qrows qh*32+nb*16+l15
    floatx4 st[2][2];
    __builtin_amdgcn_s_setprio(1);
#pragma unroll
    for (int kmb = 0; kmb < 2; ++kmb) {
      int krow = kh * 32 + kmb * 16 + l15;
      bf16x8 ak0 = *(const bf16x8*)&ks[krow * 64 + ((quad ^ sw7) * 8)];
      bf16x8 ak1 = *(const bf16x8*)&ks[krow * 64 + (((4 + quad) ^ sw7) * 8)];
#pragma unroll
      for (int nb = 0; nb < 2; ++nb) {
        floatx4 z = (floatx4){0.f, 0.f, 0.f, 0.f};
        z = __builtin_amdgcn_mfma_f32_16x16x32_bf16(ak0, qf[nb][0], z, 0, 0, 0);
        z = __builtin_amdgcn_mfma_f32_16x16x32_bf16(ak1, qf[nb][1], z, 0, 0, 0);
        st[kmb][nb] = z;
      }
    }
    __builtin_amdgcn_s_setprio(0);

    // exp2 + pack P into MFMA-B layout (permutation trick, in-register).
    // raw v_exp_f32 + raw v_cvt_pk_bf16_f32.
    bf16x8 bp[2];
#pragma unroll
    for (int nb = 0; nb < 2; ++nb) {
      float p00 = __builtin_amdgcn_exp2f(st[0][nb][0]);
      float p01 = __builtin_amdgcn_exp2f(st[0][nb][1]);
      float p02 = __builtin_amdgcn_exp2f(st[0][nb][2]);
      float p03 = __builtin_amdgcn_exp2f(st[0][nb][3]);
      float p10 = __builtin_amdgcn_exp2f(st[1][nb][0]);
      float p11 = __builtin_amdgcn_exp2f(st[1][nb][1]);
      float p12 = __builtin_amdgcn_exp2f(st[1][nb][2]);
      float p13 = __builtin_amdgcn_exp2f(st[1][nb][3]);
      l_acc[nb] += ((p00 + p01) + (p02 + p03)) + ((p10 + p11) + (p12 + p13));
      union { bf16x8 v; unsigned u[4]; } pu;
      pu.u[0] = pk_asm(p00, p01);
      pu.u[1] = pk_asm(p02, p03);
      pu.u[2] = pk_asm(p10, p11);
      pu.u[3] = pk_asm(p12, p13);
      bp[nb] = pu.v;
    }

    // O^T += V^T(perm) . P(perm): A elem j = Vt[d][kh*32+(j>>2)*16+quad*4+(j&3)]
    const int cb0 = kh * 4 + (quad >> 1);
    const int cb1 = cb0 + 2;
    const int sub = (quad & 1) * 4;
    __builtin_amdgcn_s_setprio(1);
#pragma unroll
    for (int dmb = 0; dmb < 4; ++dmb) {
      int vr = (dmb * 16 + l15) * 64;
      union { bf16x8 v; uint2 d2[2]; } au;
      au.d2[0] = *(const uint2*)&vs[vr + ((cb0 ^ sw7) * 8) + sub];
      au.d2[1] = *(const uint2*)&vs[vr + ((cb1 ^ sw7) * 8) + sub];
#pragma unroll
      for (int nb = 0; nb < 2; ++nb)
        o[dmb][nb] = __builtin_amdgcn_mfma_f32_16x16x32_bf16(au.v, bp[nb],
                                                             o[dmb][nb], 0, 0, 0);
    }
    __builtin_amdgcn_s_setprio(0);
  };

  for (int tt = 0; tt < SS / 64; tt += 2) {
    // half 0: prefetch tile tt+1 -> buf1 (tt+1 <= 31 always), compute buf0
    {
      const int k1 = (tt + 1) * 64 * HDD;  // uniform
      const int v1 = (tt + 1) * 64;        // uniform
      gload_lds16(Kt + k1 + koff0, kd0 + 4096);
      gload_lds16(Kt + k1 + koff1, kd1 + 4096);
      gload_lds16(Vt + v1 + voff0, kd0 + 12288);
      gload_lds16(Vt + v1 + voff1, kd1 + 12288);
    }
    tile_compute(Ks0, Vs0);
    __syncthreads();

    // half 1: prefetch tile tt+2 -> buf0 (guarded), compute buf1
    if (tt < SS / 64 - 2) {
      const int k2 = (tt + 2) * 64 * HDD;
      const int v2 = (tt + 2) * 64;
      gload_lds16(Kt + k2 + koff0, kd0);
      gload_lds16(Kt + k2 + koff1, kd1);
      gload_lds16(Vt + v2 + voff0, kd0 + 8192);
      gload_lds16(Vt + v2 + voff1, kd1 + 8192);
    }
    tile_compute(Ks1, Vs1);
    __syncthreads();
  }

  // ---- epilogue: combine key-halves ----
  // l: reduce over quads (16 keys of this wave), publish per-wave partial
#pragma unroll
  for (int nb = 0; nb < 2; ++nb) {
    l_acc[nb] += __shfl_xor(l_acc[nb], 16);
    l_acc[nb] += __shfl_xor(l_acc[nb], 32);
  }
  if (quad == 0) {
    lpart[wv * 32 + l15] = l_acc[0];
    lpart[wv * 32 + 16 + l15] = l_acc[1];
  }
  // O: waves kh==1 publish partial (qrow-major rows of 68 fp32)
  if (kh == 1) {
    float* dst = Opart + qh * (32 * 68);
#pragma unroll
    for (int nb = 0; nb < 2; ++nb)
#pragma unroll
      for (int dmb = 0; dmb < 4; ++dmb)
        *(floatx4*)&dst[(nb * 16 + l15) * 68 + dmb * 16 + quad * 4] =
            o[dmb][nb];
  }
  __syncthreads();
  if (kh == 0) {
    const int b = bh >> 4, h = bh & 15;
    const float* src = Opart + qh * (32 * 68);
    float inv[2];
#pragma unroll
    for (int nb = 0; nb < 2; ++nb)
      inv[nb] = 1.f / (lpart[wv * 32 + nb * 16 + l15] +
                       lpart[(wv + 2) * 32 + nb * 16 + l15]);
#pragma unroll
    for (int nb = 0; nb < 2; ++nb) {
      int s = qt * 64 + qh * 32 + nb * 16 + l15;
#pragma unroll
      for (int dmb = 0; dmb < 4; ++dmb) {
        floatx4 part =
            *(const floatx4*)&src[(nb * 16 + l15) * 68 + dmb * 16 + quad * 4];
        floatx4 tot = (o[dmb][nb] + part) * inv[nb];
        uint2 w2;
        w2.x = pk_asm(tot[0], tot[1]);
        w2.y = pk_asm(tot[2], tot[3]);
        *(uint2*)&A[((size_t)(b * SS + s) * HH) + h * HDD + dmb * 16 +
                    quad * 4] = w2;
      }
    }
  }
}

// ---------------------------------------------------------------------------
extern "C" void kernel_launch(void* const* d_in, const int* in_sizes, int n_in,
                              void* d_out, int out_size, void* d_ws,
                              size_t ws_size, hipStream_t stream) {
  const float* hs = (const float*)d_in[0];
  const int* pos = (const int*)d_in[1];
  const float* Wq = (const float*)d_in[2];
  const float* bq = (const float*)d_in[3];
  const float* Wk = (const float*)d_in[4];
  const float* bk = (const float*)d_in[5];
  const float* Wv = (const float*)d_in[6];
  const float* bv = (const float*)d_in[7];
  const float* Wo = (const float*)d_in[8];
  float* out = (float*)d_out;

  u16* hs_b = (u16*)d_ws;      // 4M
  u16* wq_b = hs_b + 4194304;  // 1M each
  u16* wk_b = wq_b + 1048576;
  u16* wv_b = wk_b + 1048576;
  u16* wo_b = wv_b + 1048576;
  u16* Qb = wo_b + 1048576;    // 4M each
  u16* Kb = Qb + 4194304;
  u16* Vtb = Kb + 4194304;     // transposed V [bh][d][s]
  u16* Ab = Vtb + 4194304;
  float2* tab = (float2*)(Ab + 4194304);  // [2048][32] cos/sin

  hipLaunchKernelGGL(convert_bf, dim3(8448), dim3(256), 0, stream, hs, Wq, Wk,
                     Wv, Wo, pos, hs_b, wq_b, wk_b, wv_b, wo_b, tab);
  hipLaunchKernelGGL(mfma_gemm_qkv, dim3(192), dim3(512), 0, stream, hs_b,
                     wq_b, wk_b, wv_b, bq, bk, bv, tab, Qb, Kb, Vtb);
  hipLaunchKernelGGL(attn_mfma, dim3(32, 32), dim3(256), 0, stream, Qb, Kb,
                     Vtb, Ab);
  hipLaunchKernelGGL(gemm_out, dim3(256), dim3(256), 0, stream, Ab, wo_b,
                     out);
}

// Round 11
// 180.593 us; speedup vs baseline: 1.1597x; 1.0079x over previous
//
#include <hip/hip_runtime.h>
#include <hip/hip_bf16.h>
#include <math.h>

#define SS 2048
#define HH 1024
#define NHH 16
#define HDD 64
#define BH 32
#define MM 4096

typedef unsigned short u16;
using bf16x8 = __attribute__((ext_vector_type(8))) short;
using floatx4 = __attribute__((ext_vector_type(4))) float;

__device__ __forceinline__ u16 f2bf(float f) {
  unsigned u = __float_as_uint(f);
  u += 0x7fffu + ((u >> 16) & 1u);
  return (u16)(u >> 16);
}
__device__ __forceinline__ unsigned pk_bf16(float a, float b) {
  union { __hip_bfloat162 h2; unsigned u; } c;
  c.h2 = __float22bfloat162_rn(float2{a, b});
  return c.u;
}
// single-instruction packed f32->bf16 (RNE). No builtin on gfx950 (m240).
__device__ __forceinline__ unsigned pk_asm(float a, float b) {
  unsigned r;
  asm("v_cvt_pk_bf16_f32 %0, %1, %2" : "=v"(r) : "v"(a), "v"(b));
  return r;
}
__device__ __forceinline__ void gload_lds16(const u16* g, u16* l) {
  __builtin_amdgcn_global_load_lds(
      (const __attribute__((address_space(1))) void*)g,
      (__attribute__((address_space(3))) void*)l, 16, 0, 0);
}

// ---------------------------------------------------------------------------
// fp32 -> bf16 conversion (hs + 4 weights) + RoPE cos/sin table.
// ---------------------------------------------------------------------------
__global__ __launch_bounds__(256) void convert_bf(
    const float* __restrict__ hs, const float* __restrict__ wq,
    const float* __restrict__ wk, const float* __restrict__ wv,
    const float* __restrict__ wo, const int* __restrict__ pos,
    u16* __restrict__ hs_b, u16* __restrict__ wq_b, u16* __restrict__ wk_b,
    u16* __restrict__ wv_b, u16* __restrict__ wo_b,
    float2* __restrict__ tab) {
  int g = blockIdx.x * 256 + threadIdx.x;
  if (g < 2097152) {
    const float* src;
    u16* dst;
    int off;
    if (g < 1048576) {
      src = hs; dst = hs_b; off = g;
    } else {
      int t = g - 1048576;
      int w = t >> 18;
      off = t & 262143;
      src = (w == 0) ? wq : (w == 1) ? wk : (w == 2) ? wv : wo;
      dst = (w == 0) ? wq_b : (w == 1) ? wk_b : (w == 2) ? wv_b : wo_b;
    }
    float4 v = ((const float4*)src)[off];
    ushort4 o = make_ushort4(f2bf(v.x), f2bf(v.y), f2bf(v.z), f2bf(v.w));
    ((ushort4*)dst)[off] = o;
  } else {
    int idx = g - 2097152;  // 0..65535
    int s = idx >> 5, j = idx & 31;
    float p = (float)pos[s];
    const float c0 = 13.287712379549449f / 32.0f;  // log2(10000)/32
    float f = p * exp2f(-(float)j * c0);
    float sn, cs;
    sincosf(f, &sn, &cs);
    tab[idx] = float2{cs, sn};
  }
}

// ---------------------------------------------------------------------------
// QKV GEMM, 8-phase 256x256 schedule (T2+T3+T4+T5), BK=64, 8 waves (2Mx4N),
// 128 KB STATIC LDS double-buffer, counted vmcnt(6) once per K-tile.
// (unchanged from R3 — verified correct; limited by 192/256 CU fill)
// ---------------------------------------------------------------------------
__global__ __launch_bounds__(512, 2) void mfma_gemm_qkv(
    const u16* __restrict__ X, const u16* __restrict__ W0,
    const u16* __restrict__ W1, const u16* __restrict__ W2,
    const float* __restrict__ b0, const float* __restrict__ b1,
    const float* __restrict__ b2, const float2* __restrict__ tab,
    u16* __restrict__ O0, u16* __restrict__ O1, u16* __restrict__ O2) {
  __shared__ __align__(16) u16 lds[65536];  // 128 KB static
  const int tid = threadIdx.x;
  const int lane = tid & 63;
  const int wv = __builtin_amdgcn_readfirstlane(tid >> 6);
  const int l15 = lane & 15, quad = lane >> 4;
  const int sw7 = l15 & 7;
  const int wm = wv >> 2, wn = wv & 3;
  const int r8 = lane >> 3, c7 = lane & 7;

  // XCD-aware bijective swizzle: XCD x gets 24 contiguous (by,bx) tiles.
  int wg = blockIdx.x;
  int swz = (wg & 7) * 24 + (wg >> 3);
  int bx = swz % 12, by = swz / 12;
  const int m0 = by * 256;
  const int n0g = bx * 256;
  const int wsel = n0g >> 10;
  const int n0 = n0g & 1023;
  const u16* Wsel = (wsel == 1) ? W1 : (wsel == 2) ? W2 : W0;
  const float* bsel = (wsel == 1) ? b1 : (wsel == 2) ? b2 : b0;
  u16* Osel = (wsel == 1) ? O1 : (wsel == 2) ? O2 : O0;

  u16* const ldsA = lds;            // [buf][256][64] u16
  u16* const ldsB = lds + 32768;

  // per-unit global sources (2 gloads each), pre-swizzled chunk c7^r8
  const int csw = (c7 ^ r8) * 8;
  const int rA0 = (wv >> 2) * 128 + (wv & 3) * 16;  // UA_p0 per-wave base row
  const int rB0 = (wv >> 1) * 64 + (wv & 1) * 16;   // UB_p0 per-wave base row
  const u16* gA0a = X + (size_t)(m0 + rA0 + r8) * HH + csw;
  const u16* gA0b = gA0a + 8 * HH;
  const u16* gA2a = gA0a + 64 * HH;
  const u16* gA2b = gA0a + 72 * HH;
  const u16* gB0a = Wsel + (size_t)(n0 + rB0 + r8) * HH + csw;
  const u16* gB0b = gB0a + 8 * HH;
  const u16* gB1a = gB0a + 32 * HH;
  const u16* gB1b = gB0a + 40 * HH;
  // LDS dst offsets (u16), within buf (buf stride 16384)
  const int dA0 = rA0 * 64;
  const int dA2 = dA0 + 4096;   // +64 rows
  const int dB0 = rB0 * 64;
  const int dB1 = dB0 + 2048;   // +32 rows

#define STAGEU(pa, pb, base, doff, buf)                  \
  do {                                                   \
    u16* d_ = (base) + (buf) * 16384 + (doff);           \
    gload_lds16((pa), d_);                               \
    gload_lds16((pb), d_ + 512);                         \
  } while (0)

  floatx4 acc[8][4];
#pragma unroll
  for (int i = 0; i < 8; ++i)
#pragma unroll
    for (int j = 0; j < 4; ++j) acc[i][j] = (floatx4){0.f, 0.f, 0.f, 0.f};

  // prologue: tile0 all 4 units, tile1 {UA_p0, UB_p0, UA_p2} (7 units);
  // UB_p1(1) arrives at t0/p0. vmcnt(6) -> tile0 landed, tile1's 3 in flight.
  STAGEU(gA0a, gA0b, ldsA, dA0, 0);
  STAGEU(gA2a, gA2b, ldsA, dA2, 0);
  STAGEU(gB0a, gB0b, ldsB, dB0, 0);
  STAGEU(gB1a, gB1b, ldsB, dB1, 0);
  STAGEU(gA0a + 64, gA0b + 64, ldsA, dA0, 1);
  STAGEU(gB0a + 64, gB0b + 64, ldsB, dB0, 1);
  STAGEU(gA2a + 64, gA2b + 64, ldsA, dA2, 1);
  asm volatile("s_waitcnt vmcnt(6)" ::: "memory");
  __builtin_amdgcn_s_barrier();

  // running prefetch pointers (u16 offsets advance 64 per tile)
  const u16 *pUB1a = gB1a + 64, *pUB1b = gB1b + 64;      // next target: tile 1
  const u16 *pUA0a = gA0a + 128, *pUA0b = gA0b + 128;    // next target: tile 2
  const u16 *pUB0a = gB0a + 128, *pUB0b = gB0b + 128;
  const u16 *pUA2a = gA2a + 128, *pUA2b = gA2b + 128;

  bf16x8 af[4][2], bf0[2][2], bf1[2][2];

#define LOADA(Ab, hm)                                                     \
  _Pragma("unroll") for (int mb = 0; mb < 4; ++mb) {                      \
    const u16* rp_ = (Ab) + (wm * 128 + (hm) * 64 + mb * 16 + l15) * 64;  \
    af[mb][0] = *(const bf16x8*)&rp_[((quad ^ sw7) * 8)];                 \
    af[mb][1] = *(const bf16x8*)&rp_[(((4 + quad) ^ sw7) * 8)];           \
  }
#define LOADB(dst, Bb, hn)                                                \
  _Pragma("unroll") for (int nq = 0; nq < 2; ++nq) {                      \
    const u16* rp_ = (Bb) + (wn * 64 + (hn) * 32 + nq * 16 + l15) * 64;   \
    dst[nq][0] = *(const bf16x8*)&rp_[((quad ^ sw7) * 8)];                \
    dst[nq][1] = *(const bf16x8*)&rp_[(((4 + quad) ^ sw7) * 8)];          \
  }
#define MFMAQ(bfh, hm, hn)                                                \
  _Pragma("unroll") for (int mb = 0; mb < 4; ++mb)                        \
  _Pragma("unroll") for (int nq = 0; nq < 2; ++nq) {                      \
    acc[(hm) * 4 + mb][(hn) * 2 + nq] =                                   \
        __builtin_amdgcn_mfma_f32_16x16x32_bf16(                          \
            af[mb][0], bfh[nq][0], acc[(hm) * 4 + mb][(hn) * 2 + nq], 0,  \
            0, 0);                                                        \
    acc[(hm) * 4 + mb][(hn) * 2 + nq] =                                   \
        __builtin_amdgcn_mfma_f32_16x16x32_bf16(                          \
            af[mb][1], bfh[nq][1], acc[(hm) * 4 + mb][(hn) * 2 + nq], 0,  \
            0, 0);                                                        \
  }

#pragma unroll 2
  for (int t = 0; t < 16; ++t) {
    const u16* Ac = ldsA + (t & 1) * 16384;
    const u16* Bc = ldsB + (t & 1) * 16384;
    const int nb1 = (t + 1) & 1;  // buf for tile t+1
    const int nb2 = t & 1;        // buf for tile t+2
    // ---- phase 0: reads UA_p0 + UB_p0 (12 ds_read_b128), stage UB_p1(t+1)
    LOADA(Ac, 0);
    LOADB(bf0, Bc, 0);
    if (t < 15) {
      STAGEU(pUB1a, pUB1b, ldsB, dB1, nb1);
      pUB1a += 64; pUB1b += 64;
    }
    __builtin_amdgcn_s_barrier();
    asm volatile("s_waitcnt lgkmcnt(0)" ::: "memory");
    __builtin_amdgcn_s_setprio(1);
    MFMAQ(bf0, 0, 0);
    __builtin_amdgcn_s_setprio(0);
    __builtin_amdgcn_s_barrier();
    // ---- phase 1: reads UB_p1, stage UA_p0(t+2) (last read p0, closed)
    LOADB(bf1, Bc, 1);
    if (t < 14) {
      STAGEU(pUA0a, pUA0b, ldsA, dA0, nb2);
      pUA0a += 64; pUA0b += 64;
    }
    __builtin_amdgcn_s_barrier();
    asm volatile("s_waitcnt lgkmcnt(0)" ::: "memory");
    __builtin_amdgcn_s_setprio(1);
    MFMAQ(bf1, 0, 1);
    __builtin_amdgcn_s_setprio(0);
    __builtin_amdgcn_s_barrier();
    // ---- phase 2: reads UA_p2, stage UB_p0(t+2) (last read p0, closed)
    LOADA(Ac, 1);
    if (t < 14) {
      STAGEU(pUB0a, pUB0b, ldsB, dB0, nb2);
      pUB0a += 64; pUB0b += 64;
    }
    __builtin_amdgcn_s_barrier();
    asm volatile("s_waitcnt lgkmcnt(0)" ::: "memory");
    __builtin_amdgcn_s_setprio(1);
    MFMAQ(bf0, 1, 0);
    __builtin_amdgcn_s_setprio(0);
    __builtin_amdgcn_s_barrier();
    // ---- phase 3: regs only, stage UA_p2(t+2) (last read p2, closed)
    if (t < 14) {
      STAGEU(pUA2a, pUA2b, ldsA, dA2, nb2);
      pUA2a += 64; pUA2b += 64;
    }
    __builtin_amdgcn_s_setprio(1);
    MFMAQ(bf1, 1, 1);
    __builtin_amdgcn_s_setprio(0);
    if (t < 14) {
      asm volatile("s_waitcnt vmcnt(6)" ::: "memory");
      __builtin_amdgcn_s_barrier();
    } else if (t == 14) {
      asm volatile("s_waitcnt vmcnt(0)" ::: "memory");
      __builtin_amdgcn_s_barrier();
    }
  }
#undef STAGEU
#undef LOADA
#undef LOADB
#undef MFMAQ

  if (wsel < 2) {
    const float qs = (wsel == 0) ? 0.125f * 1.44269504088896f : 1.0f;
    const int colb = n0 + wn * 64;
    const int h = colb >> 6;
    const float bias0 = bsel[colb + l15];
    const float bias1 = bsel[colb + 16 + l15];
    const float bias2 = bsel[colb + 32 + l15];
    const float bias3 = bsel[colb + 48 + l15];
#pragma unroll
    for (int mb = 0; mb < 8; ++mb)
#pragma unroll
      for (int r = 0; r < 4; ++r) {
        int m = m0 + wm * 128 + mb * 16 + quad * 4 + r;
        int b = m >> 11, s = m & (SS - 1);
        float2 t0 = tab[s * 32 + l15];
        float2 t1 = tab[s * 32 + 16 + l15];
        size_t obase = ((size_t)(b * NHH + h) * SS + s) * HDD;
        float x1 = acc[mb][0][r] + bias0;
        float x2 = acc[mb][2][r] + bias2;
        Osel[obase + l15] = f2bf((x1 * t0.x - x2 * t0.y) * qs);
        Osel[obase + 32 + l15] = f2bf((x2 * t0.x + x1 * t0.y) * qs);
        float y1 = acc[mb][1][r] + bias1;
        float y2 = acc[mb][3][r] + bias3;
        Osel[obase + 16 + l15] = f2bf((y1 * t1.x - y2 * t1.y) * qs);
        Osel[obase + 48 + l15] = f2bf((y2 * t1.x + y1 * t1.y) * qs);
      }
  } else {
#pragma unroll
    for (int nb = 0; nb < 4; ++nb) {
      int col = n0 + wn * 64 + nb * 16 + l15;
      int h = col >> 6, d = col & 63;
      float bias = bsel[col];
#pragma unroll
      for (int mb = 0; mb < 8; ++mb) {
        int m = m0 + wm * 128 + mb * 16 + quad * 4;
        int b = m >> 11, s = m & (SS - 1);
        uint2 w2;
        w2.x = pk_bf16(acc[mb][nb][0] + bias, acc[mb][nb][1] + bias);
        w2.y = pk_bf16(acc[mb][nb][2] + bias, acc[mb][nb][3] + bias);
        *(uint2*)&Osel[((size_t)((b * NHH + h) * HDD + d)) * SS + s] = w2;
      }
    }
  }
}

// ---------------------------------------------------------------------------
// Final projection GEMM v2: 128x128 tile, BK=64, 4 waves, double-buffered
// 64 KB LDS, depth-2 counted prefetch. (unchanged from R5 — verified, ~14 us)
// ---------------------------------------------------------------------------
__global__ __launch_bounds__(256) void gemm_out(const u16* __restrict__ X,
                                                const u16* __restrict__ W,
                                                float* __restrict__ Ofp) {
  __shared__ __align__(16) u16 As[2][8192];  // [buf][128*64]
  __shared__ __align__(16) u16 Bs[2][8192];
  const int tid = threadIdx.x;
  const int lane = tid & 63;
  const int wv = __builtin_amdgcn_readfirstlane(tid >> 6);
  const int l15 = lane & 15, quad = lane >> 4;
  const int sw7 = l15 & 7;
  const int wm = wv >> 1, wn = wv & 1;
  const int r8 = lane >> 3, c7 = lane & 7;

  int wg = blockIdx.x;
  int swz = (wg & 7) * 32 + (wg >> 3);  // 256 % 8 == 0: bijective
  const int n0 = (swz & 7) * 128;
  const int m0 = (swz >> 3) * 128;

  const int csw = (c7 ^ r8) * 8;
  const u16* gA = X + (size_t)(m0 + wv * 32 + r8) * HH + csw;
  const u16* gB = W + (size_t)(n0 + wv * 32 + r8) * HH + csw;
  u16* const dA = &As[0][0] + (wv * 32) * 64;
  u16* const dB = &Bs[0][0] + (wv * 32) * 64;

#define STG_O(tile, buf)                                           \
  _Pragma("unroll") for (int u = 0; u < 4; ++u) {                  \
    gload_lds16(gA + (size_t)u * 8 * HH + (tile) * 64,             \
                dA + (buf) * 8192 + u * 512);                      \
    gload_lds16(gB + (size_t)u * 8 * HH + (tile) * 64,             \
                dB + (buf) * 8192 + u * 512);                      \
  }

  floatx4 acc[4][4];
#pragma unroll
  for (int i = 0; i < 4; ++i)
#pragma unroll
    for (int j = 0; j < 4; ++j) acc[i][j] = (floatx4){0.f, 0.f, 0.f, 0.f};

  STG_O(0, 0);
  STG_O(1, 1);
  asm volatile("s_waitcnt vmcnt(8)" ::: "memory");
  __builtin_amdgcn_s_barrier();

  for (int t = 0; t < 16; ++t) {
    const u16* Ac = &As[0][0] + (t & 1) * 8192;
    const u16* Bc = &Bs[0][0] + (t & 1) * 8192;
    bf16x8 af[4][2], bfr[4][2];
#pragma unroll
    for (int mb = 0; mb < 4; ++mb) {
      const u16* rp = Ac + (wm * 64 + mb * 16 + l15) * 64;
      af[mb][0] = *(const bf16x8*)&rp[(quad ^ sw7) * 8];
      af[mb][1] = *(const bf16x8*)&rp[((4 + quad) ^ sw7) * 8];
    }
#pragma unroll
    for (int nb = 0; nb < 4; ++nb) {
      const u16* rp = Bc + (wn * 64 + nb * 16 + l15) * 64;
      bfr[nb][0] = *(const bf16x8*)&rp[(quad ^ sw7) * 8];
      bfr[nb][1] = *(const bf16x8*)&rp[((4 + quad) ^ sw7) * 8];
    }
    __builtin_amdgcn_s_barrier();  // all waves' reads of this buf issued
    if (t < 14) STG_O(t + 2, t & 1);
    asm volatile("s_waitcnt lgkmcnt(0)" ::: "memory");
    __builtin_amdgcn_sched_barrier(0);
    __builtin_amdgcn_s_setprio(1);
#pragma unroll
    for (int mb = 0; mb < 4; ++mb)
#pragma unroll
      for (int nb = 0; nb < 4; ++nb) {
        acc[mb][nb] = __builtin_amdgcn_mfma_f32_16x16x32_bf16(
            af[mb][0], bfr[nb][0], acc[mb][nb], 0, 0, 0);
        acc[mb][nb] = __builtin_amdgcn_mfma_f32_16x16x32_bf16(
            af[mb][1], bfr[nb][1], acc[mb][nb], 0, 0, 0);
      }
    __builtin_amdgcn_s_setprio(0);
    if (t < 14) {
      asm volatile("s_waitcnt vmcnt(8)" ::: "memory");
    } else if (t == 14) {
      asm volatile("s_waitcnt vmcnt(0)" ::: "memory");
    }
    __builtin_amdgcn_s_barrier();
  }
#undef STG_O

#pragma unroll
  for (int mb = 0; mb < 4; ++mb)
#pragma unroll
    for (int r = 0; r < 4; ++r) {
      int m = m0 + wm * 64 + mb * 16 + quad * 4 + r;
#pragma unroll
      for (int nb = 0; nb < 4; ++nb)
        Ofp[(size_t)m * HH + n0 + wn * 64 + nb * 16 + l15] = acc[mb][nb][r];
    }
}

// ---------------------------------------------------------------------------
// Flash attention, key-partitioned quadrant scheme (verified R5 structure).
// R11: l-sum moved from VALU to MFMA — l_accv[nb] = mfma(ones, bp[nb], .)
// computes column sums of P exactly (sum over k is permutation-invariant;
// A=ones is layout-invariant). Replaces 16 serial v_add_f32/tile on the
// 42%-busy VALU with 2 MFMAs on the 30%-busy matrix pipe, and deletes the
// epilogue shfl-reduce (every lane holds the full key-half sum).
// ---------------------------------------------------------------------------
__global__ __launch_bounds__(256, 4) void attn_mfma(const u16* __restrict__ Qg,
                                                    const u16* __restrict__ Kg,
                                                    const u16* __restrict__ Vtg,
                                                    u16* __restrict__ A) {
  __shared__ __align__(16) u16 smem[16384];  // 32 KB
  u16* const Ks0 = smem;
  u16* const Ks1 = smem + 4096;
  u16* const Vs0 = smem + 8192;
  u16* const Vs1 = smem + 12288;
  float* const lpart = (float*)smem;        // [4][32]
  float* const Opart = (float*)smem + 128;  // [2][32][68]

  const int tid = threadIdx.x;
  const int lane = tid & 63;
  const int wv = __builtin_amdgcn_readfirstlane(tid >> 6);
  const int l15 = lane & 15, quad = lane >> 4;
  const int sw7 = l15 & 7;
  const int bh = blockIdx.x, qt = blockIdx.y;
  const size_t hb = (size_t)bh * SS * HDD;  // Q,K [bh][s][d]; Vt [bh][d][s]
  const int kh = wv >> 1;  // key-half
  const int qh = wv & 1;   // qrow-half

  // staging geometry: wave covers segs {wv*2, wv*2+1} of 8 rows each.
  // uniform bases + loop-invariant per-lane offsets (scalar tile advance).
  const int r8 = lane >> 3, c7 = lane & 7;
  const int cs = (c7 ^ r8) * 8;  // XOR-swizzled chunk (u16 offset)
  const u16* const Kt = Kg + hb;
  const u16* const Vt = Vtg + hb;
  const int row0 = (wv * 2 + 0) * 8 + r8;
  const int row1 = (wv * 2 + 1) * 8 + r8;
  const int koff0 = row0 * HDD + cs;
  const int koff1 = row1 * HDD + cs;
  const int voff0 = row0 * SS + cs;
  const int voff1 = row1 * SS + cs;
  u16* const kd0 = smem + (wv * 2 + 0) * 512;  // LDS dst (buf-relative)
  u16* const kd1 = smem + (wv * 2 + 1) * 512;

  // stage Q (64x64) into Ks1 + first K/V tile into buf0
  gload_lds16(Qg + hb + qt * 4096 + koff0, kd0 + 4096);
  gload_lds16(Qg + hb + qt * 4096 + koff1, kd1 + 4096);
  gload_lds16(Kt + koff0, kd0);
  gload_lds16(Kt + koff1, kd1);
  gload_lds16(Vt + voff0, kd0 + 8192);
  gload_lds16(Vt + voff1, kd1 + 8192);
  __syncthreads();

  // Q B-frags (loop-invariant): qrows qh*32 + nb*16 + l15
  bf16x8 qf[2][2];
#pragma unroll
  for (int nb = 0; nb < 2; ++nb)
#pragma unroll
    for (int h2 = 0; h2 < 2; ++h2)
      qf[nb][h2] = *(const bf16x8*)&Ks1[(qh * 32 + nb * 16 + l15) * 64 +
                                        (((h2 * 4 + quad) ^ sw7) * 8)];
  __syncthreads();  // qf reads complete before t=1 staging overwrites Ks1

  // ones A-fragment (bf16 1.0 = 0x3F80) for the MFMA l-sum
  const short ob = (short)0x3F80;
  const bf16x8 ones = (bf16x8){ob, ob, ob, ob, ob, ob, ob, ob};

  floatx4 l_accv[2];
  l_accv[0] = (floatx4){0.f, 0.f, 0.f, 0.f};
  l_accv[1] = (floatx4){0.f, 0.f, 0.f, 0.f};
  floatx4 o[4][2];
#pragma unroll
  for (int dmb = 0; dmb < 4; ++dmb)
#pragma unroll
    for (int nb = 0; nb < 2; ++nb) o[dmb][nb] = (floatx4){0.f, 0.f, 0.f, 0.f};

  // one key-tile compute, statically-addressed buffers
  auto tile_compute = [&](const u16* ks, const u16* vs) {
    // S^T quadrant: keys kh*32+kmb*16+quad*4+r, qrows qh*32+nb*16+l15
    floatx4 st[2][2];
    __builtin_amdgcn_s_setprio(1);
#pragma unroll
    for (int kmb = 0; kmb < 2; ++kmb) {
      int krow = kh * 32 + kmb * 16 + l15;
      bf16x8 ak0 = *(const bf16x8*)&ks[krow * 64 + ((quad ^ sw7) * 8)];
      bf16x8 ak1 = *(const bf16x8*)&ks[krow * 64 + (((4 + quad) ^ sw7) * 8)];
#pragma unroll
      for (int nb = 0; nb < 2; ++nb) {
        floatx4 z = (floatx4){0.f, 0.f, 0.f, 0.f};
        z = __builtin_amdgcn_mfma_f32_16x16x32_bf16(ak0, qf[nb][0], z, 0, 0, 0);
        z = __builtin_amdgcn_mfma_f32_16x16x32_bf16(ak1, qf[nb][1], z, 0, 0, 0);
        st[kmb][nb] = z;
      }
    }
    __builtin_amdgcn_s_setprio(0);

    // exp2 + pack P into MFMA-B layout (permutation trick, in-register).
    bf16x8 bp[2];
#pragma unroll
    for (int nb = 0; nb < 2; ++nb) {
      float p00 = __builtin_amdgcn_exp2f(st[0][nb][0]);
      float p01 = __builtin_amdgcn_exp2f(st[0][nb][1]);
      float p02 = __builtin_amdgcn_exp2f(st[0][nb][2]);
      float p03 = __builtin_amdgcn_exp2f(st[0][nb][3]);
      float p10 = __builtin_amdgcn_exp2f(st[1][nb][0]);
      float p11 = __builtin_amdgcn_exp2f(st[1][nb][1]);
      float p12 = __builtin_amdgcn_exp2f(st[1][nb][2]);
      float p13 = __builtin_amdgcn_exp2f(st[1][nb][3]);
      union { bf16x8 v; unsigned u[4]; } pu;
      pu.u[0] = pk_asm(p00, p01);
      pu.u[1] = pk_asm(p02, p03);
      pu.u[2] = pk_asm(p10, p11);
      pu.u[3] = pk_asm(p12, p13);
      bp[nb] = pu.v;
    }

    // O^T += V^T(perm) . P(perm); l-sum on the matrix pipe.
    const int cb0 = kh * 4 + (quad >> 1);
    const int cb1 = cb0 + 2;
    const int sub = (quad & 1) * 4;
    __builtin_amdgcn_s_setprio(1);
    l_accv[0] = __builtin_amdgcn_mfma_f32_16x16x32_bf16(ones, bp[0],
                                                        l_accv[0], 0, 0, 0);
    l_accv[1] = __builtin_amdgcn_mfma_f32_16x16x32_bf16(ones, bp[1],
                                                        l_accv[1], 0, 0, 0);
#pragma unroll
    for (int dmb = 0; dmb < 4; ++dmb) {
      int vr = (dmb * 16 + l15) * 64;
      union { bf16x8 v; uint2 d2[2]; } au;
      au.d2[0] = *(const uint2*)&vs[vr + ((cb0 ^ sw7) * 8) + sub];
      au.d2[1] = *(const uint2*)&vs[vr + ((cb1 ^ sw7) * 8) + sub];
#pragma unroll
      for (int nb = 0; nb < 2; ++nb)
        o[dmb][nb] = __builtin_amdgcn_mfma_f32_16x16x32_bf16(au.v, bp[nb],
                                                             o[dmb][nb], 0, 0, 0);
    }
    __builtin_amdgcn_s_setprio(0);
  };

  for (int tt = 0; tt < SS / 64; tt += 2) {
    // half 0: prefetch tile tt+1 -> buf1 (tt+1 <= 31 always), compute buf0
    {
      const int k1 = (tt + 1) * 64 * HDD;  // uniform
      const int v1 = (tt + 1) * 64;        // uniform
      gload_lds16(Kt + k1 + koff0, kd0 + 4096);
      gload_lds16(Kt + k1 + koff1, kd1 + 4096);
      gload_lds16(Vt + v1 + voff0, kd0 + 12288);
      gload_lds16(Vt + v1 + voff1, kd1 + 12288);
    }
    tile_compute(Ks0, Vs0);
    __syncthreads();

    // half 1: prefetch tile tt+2 -> buf0 (guarded), compute buf1
    if (tt < SS / 64 - 2) {
      const int k2 = (tt + 2) * 64 * HDD;
      const int v2 = (tt + 2) * 64;
      gload_lds16(Kt + k2 + koff0, kd0);
      gload_lds16(Kt + k2 + koff1, kd1);
      gload_lds16(Vt + v2 + voff0, kd0 + 8192);
      gload_lds16(Vt + v2 + voff1, kd1 + 8192);
    }
    tile_compute(Ks1, Vs1);
    __syncthreads();
  }

  // ---- epilogue: combine key-halves ----
  // l: every lane holds the wave's full key-half sum (MFMA l-sum).
  if (quad == 0) {
    lpart[wv * 32 + l15] = l_accv[0][0];
    lpart[wv * 32 + 16 + l15] = l_accv[1][0];
  }
  // O: waves kh==1 publish partial (qrow-major rows of 68 fp32)
  if (kh == 1) {
    float* dst = Opart + qh * (32 * 68);
#pragma unroll
    for (int nb = 0; nb < 2; ++nb)
#pragma unroll
      for (int dmb = 0; dmb < 4; ++dmb)
        *(floatx4*)&dst[(nb * 16 + l15) * 68 + dmb * 16 + quad * 4] =
            o[dmb][nb];
  }
  __syncthreads();
  if (kh == 0) {
    const int b = bh >> 4, h = bh & 15;
    const float* src = Opart + qh * (32 * 68);
    float inv[2];
#pragma unroll
    for (int nb = 0; nb < 2; ++nb)
      inv[nb] = 1.f / (lpart[wv * 32 + nb * 16 + l15] +
                       lpart[(wv + 2) * 32 + nb * 16 + l15]);
#pragma unroll
    for (int nb = 0; nb < 2; ++nb) {
      int s = qt * 64 + qh * 32 + nb * 16 + l15;
#pragma unroll
      for (int dmb = 0; dmb < 4; ++dmb) {
        floatx4 part =
            *(const floatx4*)&src[(nb * 16 + l15) * 68 + dmb * 16 + quad * 4];
        floatx4 tot = (o[dmb][nb] + part) * inv[nb];
        uint2 w2;
        w2.x = pk_asm(tot[0], tot[1]);
        w2.y = pk_asm(tot[2], tot[3]);
        *(uint2*)&A[((size_t)(b * SS + s) * HH) + h * HDD + dmb * 16 +
                    quad * 4] = w2;
      }
    }
  }
}

// ---------------------------------------------------------------------------
extern "C" void kernel_launch(void* const* d_in, const int* in_sizes, int n_in,
                              void* d_out, int out_size, void* d_ws,
                              size_t ws_size, hipStream_t stream) {
  const float* hs = (const float*)d_in[0];
  const int* pos = (const int*)d_in[1];
  const float* Wq = (const float*)d_in[2];
  const float* bq = (const float*)d_in[3];
  const float* Wk = (const float*)d_in[4];
  const float* bk = (const float*)d_in[5];
  const float* Wv = (const float*)d_in[6];
  const float* bv = (const float*)d_in[7];
  const float* Wo = (const float*)d_in[8];
  float* out = (float*)d_out;

  u16* hs_b = (u16*)d_ws;      // 4M
  u16* wq_b = hs_b + 4194304;  // 1M each
  u16* wk_b = wq_b + 1048576;
  u16* wv_b = wk_b + 1048576;
  u16* wo_b = wv_b + 1048576;
  u16* Qb = wo_b + 1048576;    // 4M each
  u16* Kb = Qb + 4194304;
  u16* Vtb = Kb + 4194304;     // transposed V [bh][d][s]
  u16* Ab = Vtb + 4194304;
  float2* tab = (float2*)(Ab + 4194304);  // [2048][32] cos/sin

  hipLaunchKernelGGL(convert_bf, dim3(8448), dim3(256), 0, stream, hs, Wq, Wk,
                     Wv, Wo, pos, hs_b, wq_b, wk_b, wv_b, wo_b, tab);
  hipLaunchKernelGGL(mfma_gemm_qkv, dim3(192), dim3(512), 0, stream, hs_b,
                     wq_b, wk_b, wv_b, bq, bk, bv, tab, Qb, Kb, Vtb);
  hipLaunchKernelGGL(attn_mfma, dim3(32, 32), dim3(256), 0, stream, Qb, Kb,
                     Vtb, Ab);
  hipLaunchKernelGGL(gemm_out, dim3(256), dim3(256), 0, stream, Ab, wo_b,
                     out);
}